// Round 14
// baseline (890.828 us; speedup 1.0000x reference)
//
#include <hip/hip_runtime.h>
#include <cstdint>

#define BB 256
#define TT 1000
#define DD 256
#define SS 10
#define HH 64
#define CC 100
// 2*log2(e): accumulate z2' = PRE*z so tanh(z) = 1 - 2/(exp2(z2')+1)
#define PRE 2.885390081777927f

typedef float f32x2 __attribute__((ext_vector_type(2)));
typedef float f32x4 __attribute__((ext_vector_type(4)));

__device__ __forceinline__ f32x2 lo2(f32x4 v) {
  return __builtin_shufflevector(v, v, 0, 1);
}
__device__ __forceinline__ f32x2 hi2(f32x4 v) {
  return __builtin_shufflevector(v, v, 2, 3);
}

// ---------------------------------------------------------------------------
// proj for one segment, run by waves 1..7. k-split: wave1 k[0,40), waves 2..7
// k[40+36(w-2), +36). W-slice in regs (PRE-prescaled); x rows read as
// wave-uniform broadcast b128 loads, double-buffered across c; partial dot
// accumulated with pk_fma and combined via LDS atomicAdd (ds_add_f32) into
// dst (bias-pre-initialized). Adds commute -> no cross-wave ordering needed.
// ---------------------------------------------------------------------------
__device__ __forceinline__ void proj_seg(
    const float* __restrict__ x, const float* __restrict__ W_ih,
    float (*__restrict__ dst)[66], int b, int sp, int w, int lane) {
  const int ko = (w == 1) ? 0 : (40 + 36 * (w - 2));
  const bool full = (w == 1);  // wave1 handles 40 k, others 36

  f32x2 Wk[20];
  const float* wrow = W_ih + ((size_t)sp * HH + lane) * DD + ko;
#pragma unroll
  for (int q = 0; q < 9; ++q) {
    const f32x4 v = *(const f32x4*)(wrow + 4 * q);
    Wk[2 * q]     = (f32x2){PRE * v.x, PRE * v.y};
    Wk[2 * q + 1] = (f32x2){PRE * v.z, PRE * v.w};
  }
  if (full) {
    const f32x4 v = *(const f32x4*)(wrow + 36);
    Wk[18] = (f32x2){PRE * v.x, PRE * v.y};
    Wk[19] = (f32x2){PRE * v.z, PRE * v.w};
  }

  const float* xr = x + ((size_t)b * TT + (size_t)sp * CC) * DD + ko;
  f32x4 xa[10], xb[10];
#pragma unroll
  for (int q = 0; q < 9; ++q) xa[q] = *(const f32x4*)(xr + 4 * q);
  if (full) xa[9] = *(const f32x4*)(xr + 36);

  for (int c2 = 0; c2 < CC; c2 += 2) {
    const float* xr1 = xr + (size_t)(c2 + 1) * DD;
#pragma unroll
    for (int q = 0; q < 9; ++q) xb[q] = *(const f32x4*)(xr1 + 4 * q);
    if (full) xb[9] = *(const f32x4*)(xr1 + 36);
    {  // compute c2 from xa
      f32x2 a0 = {0.f, 0.f}, a1 = {0.f, 0.f};
#pragma unroll
      for (int q = 0; q < 9; ++q) {
        a0 = __builtin_elementwise_fma(Wk[2 * q], lo2(xa[q]), a0);
        a1 = __builtin_elementwise_fma(Wk[2 * q + 1], hi2(xa[q]), a1);
      }
      if (full) {
        a0 = __builtin_elementwise_fma(Wk[18], lo2(xa[9]), a0);
        a1 = __builtin_elementwise_fma(Wk[19], hi2(xa[9]), a1);
      }
      const f32x2 t = a0 + a1;
      atomicAdd(&dst[c2][lane], t.x + t.y);
    }
    if (c2 + 2 < CC) {  // prefetch c2+2 into xa
      const float* xr2 = xr + (size_t)(c2 + 2) * DD;
#pragma unroll
      for (int q = 0; q < 9; ++q) xa[q] = *(const f32x4*)(xr2 + 4 * q);
      if (full) xa[9] = *(const f32x4*)(xr2 + 36);
    }
    {  // compute c2+1 from xb
      f32x2 a0 = {0.f, 0.f}, a1 = {0.f, 0.f};
#pragma unroll
      for (int q = 0; q < 9; ++q) {
        a0 = __builtin_elementwise_fma(Wk[2 * q], lo2(xb[q]), a0);
        a1 = __builtin_elementwise_fma(Wk[2 * q + 1], hi2(xb[q]), a1);
      }
      if (full) {
        a0 = __builtin_elementwise_fma(Wk[18], lo2(xb[9]), a0);
        a1 = __builtin_elementwise_fma(Wk[19], hi2(xb[9]), a1);
      }
      const f32x2 t = a0 + a1;
      atomicAdd(&dst[c2 + 1][lane], t.x + t.y);
    }
  }
}

// ---------------------------------------------------------------------------
// Fused kernel: one block (8 waves) per batch element.
//   wave 0:   recurrence (R13 pk_fma step, xp from LDS) + fused head
//   waves 1-7: proj of segment s+1 into buf[(s+1)&1] (overlapped)
// buf[p][c][:] holds xp of segment s (p=s&1) and is overwritten in place by
// h at step c (xp slot dead after its step) -> hist and xp share storage.
// Per segment: [init buf[1-p] with bias(s+1)] SYNC [rec(s) || proj(s+1)] SYNC.
// h crosses segments via hrow (wave0-written, wave0-read).
// ---------------------------------------------------------------------------
__global__ __launch_bounds__(512, 1) void fused_kernel(
    const float* __restrict__ x, const float* __restrict__ W_ih,
    const float* __restrict__ W_hh, const float* __restrict__ b_ih,
    const float* __restrict__ b_hh, const float* __restrict__ fc_w,
    const float* __restrict__ fc_b, float* __restrict__ y) {
  __shared__ float buf[2][CC][66];
  __shared__ float hrow[64];
  const int b = blockIdx.x;
  const int tid = threadIdx.x;
  const int lane = tid & 63;
  const int w = tid >> 6;

  // prologue: bias-init buf0 (segment 0), h0 = 0
  if (tid < 64) hrow[tid] = 0.f;
  for (int i = tid; i < CC * HH; i += 512) {
    const int c = i >> 6, hh = i & 63;
    buf[0][c][hh] = PRE * (b_ih[hh] + b_hh[hh]);
  }
  __syncthreads();
  if (w >= 1) proj_seg(x, W_ih, buf[0], b, 0, w, lane);
  __syncthreads();

  for (int s = 0; s < SS; ++s) {
    const int p = s & 1;
    // init window: bias-init buf[1-p] for segment s+1 (free: rec+head of s-1 done)
    if (s + 1 < SS) {
      for (int i = tid; i < CC * HH; i += 512) {
        const int c = i >> 6, hh = i & 63;
        buf[1 - p][c][hh] =
            PRE * (b_ih[(s + 1) * HH + hh] + b_hh[(s + 1) * HH + hh]);
      }
    }
    __syncthreads();

    if (w == 0) {
      // ---- recurrence (R13 structure; xp from LDS, 1-deep prefetch)
      f32x2 Wp[32];
      const float* wr = W_hh + ((size_t)s * HH + lane) * HH;
#pragma unroll
      for (int j = 0; j < 16; ++j) {
        const f32x4 v = *(const f32x4*)(wr + 4 * j);
        Wp[2 * j]     = (f32x2){PRE * v.x, PRE * v.y};
        Wp[2 * j + 1] = (f32x2){PRE * v.z, PRE * v.w};
      }
      float h = 0.f;
      float xq = buf[p][0][lane];
#pragma unroll 4
      for (int c = 0; c < CC; ++c) {
        const float xq_next = buf[p][(c + 1 < CC) ? c + 1 : c][lane];
        const float* hb = (c == 0) ? hrow : &buf[p][c - 1][0];
        f32x2 a0 = {xq, 0.f}, a1 = {0.f, 0.f};
#pragma unroll
        for (int j4 = 0; j4 < 16; ++j4) {
          const f32x4 hv = *(const f32x4*)(hb + 4 * j4);
          a0 = __builtin_elementwise_fma(Wp[2 * j4], lo2(hv), a0);
          a1 = __builtin_elementwise_fma(Wp[2 * j4 + 1], hi2(hv), a1);
        }
        const f32x2 t = a0 + a1;
        const float e = __builtin_amdgcn_exp2f(t.x + t.y);  // exp(2z)
        h = 1.f - 2.f * __builtin_amdgcn_rcpf(e + 1.f);
        buf[p][c][lane] = h;  // xp[c] consumed -> slot becomes hist[c]
        xq = xq_next;
      }
      hrow[lane] = h;  // segment handoff for step 0 broadcast
      // ---- fused head
      const float fb = fc_b[s];
      const float* fw = fc_w + s * HH;
#pragma unroll
      for (int base = 0; base < CC; base += 64) {
        const int l = base + lane;
        if (l < CC) {
          float z = fb;
#pragma unroll
          for (int i = 0; i < 64; i += 4) {
            const f32x4 hv = *(const f32x4*)&buf[p][l][i];
            z += hv.x * fw[i] + hv.y * fw[i + 1] + hv.z * fw[i + 2] +
                 hv.w * fw[i + 3];
          }
          y[(size_t)b * TT + s * CC + l] =
              __builtin_amdgcn_rcpf(1.f + __expf(-z));
        }
      }
    } else if (s + 1 < SS) {
      proj_seg(x, W_ih, buf[1 - p], b, s + 1, w, lane);
    }
    __syncthreads();
  }
}

extern "C" void kernel_launch(void* const* d_in, const int* in_sizes, int n_in,
                              void* d_out, int out_size, void* d_ws,
                              size_t ws_size, hipStream_t stream) {
  const float* x    = (const float*)d_in[0];
  const float* W_ih = (const float*)d_in[1];
  const float* W_hh = (const float*)d_in[2];
  const float* b_ih = (const float*)d_in[3];
  const float* b_hh = (const float*)d_in[4];
  const float* fc_w = (const float*)d_in[5];
  const float* fc_b = (const float*)d_in[6];
  float* y = (float*)d_out;

  fused_kernel<<<256, 512, 0, stream>>>(x, W_ih, W_hh, b_ih, b_hh,
                                        fc_w, fc_b, y);
}